// Round 9
// baseline (280.126 us; speedup 1.0000x reference)
//
#include <hip/hip_runtime.h>

#define N_NODES 100000
#define N_EDGES 1600000
#define NB 391          // coarse buckets of 256 nodes
#define BCAP 5120       // per-bucket capacity (expected 4092, 16-sigma headroom)
#define PART_BLOCKS 250
#define EPB 6400        // edges per partition block (250*6400 = 1.6M exact)
#define GSTRIDE 16      // global cursor pad: 1 counter per 64B line (atomic channel parallelism)

typedef __attribute__((ext_vector_type(8))) short short8;   // 8 bf16 (4 VGPR) MFMA frag
typedef __attribute__((ext_vector_type(4))) float f32x4;    // MFMA accumulator

__device__ inline unsigned short f2bf(float f) {
    unsigned int u = __builtin_bit_cast(unsigned int, f);
    u += 0x7fffu + ((u >> 16) & 1u);   // round-to-nearest-even
    return (unsigned short)(u >> 16);
}
__device__ inline float bf2f(unsigned short h) {
    unsigned int u = ((unsigned int)h) << 16;
    return __builtin_bit_cast(float, u);
}

// ---- partition (blocks 0..249, 1024 thr): LDS counting-sort -> COALESCED writes.
//      (R7: 42 -> ~33 us; write-amplification halved. Residual cost = LDS atomic
//      scatter + barrier chain.) Failed variants (do not retry): 800 blocks (R1),
//      global degS atomics (R3), TLP beyond 16 waves (R6 flat).
//      blocks 250..252: pack W1/W2 bf16 B-fragments. ----
__global__ __launch_bounds__(1024) void k_part(const int* __restrict__ src, const int* __restrict__ dst,
                                               int* __restrict__ gcurD, int* __restrict__ gcurS,
                                               unsigned int* __restrict__ ebuf,
                                               unsigned char* __restrict__ ebufS,
                                               const float* __restrict__ W1, const float* __restrict__ W2,
                                               unsigned short* __restrict__ Wp1, unsigned short* __restrict__ Wp2) {
    if (blockIdx.x >= PART_BLOCKS) {          // ---- pack_w blocks ----
        int i = (blockIdx.x - PART_BLOCKS) * 1024 + threadIdx.x;   // 3072 total
        if (i < 2048) {                       // W1: 16 kq x 128 c
            int kq = i >> 7, c = i & 127;
#pragma unroll
            for (int j = 0; j < 8; j++) Wp1[i * 8 + j] = f2bf(W1[(kq * 8 + j) * 128 + c]);
        } else if (i < 3072) {                // W2: 16 kq x 64 c
            int i2 = i - 2048;
            int kq = i2 >> 6, c = i2 & 63;
#pragma unroll
            for (int j = 0; j < 8; j++) Wp2[i2 * 8 + j] = f2bf(W2[(kq * 8 + j) * 64 + c]);
        }
        return;
    }
    __shared__ uint2 est[EPB];                       // 51.2 KB staged (src,dst)
    __shared__ unsigned int sortedPk[EPB];           // 25.6 KB dst-sorted records
    __shared__ unsigned short bIdD[EPB];             // 12.8 KB bucket id per slot
    __shared__ unsigned short bIdS[EPB];             // 12.8 KB (src keying)
    __shared__ unsigned char sByte[EPB];             //  6.4 KB src-sorted bytes
    __shared__ int histD[NB], histS[NB], startD[NB], startS[NB];
    __shared__ int gbD[NB], gbS[NB], cursD[NB], cursS[NB];
    __shared__ int s1[256];
    int t = threadIdx.x;
    for (int i = t; i < NB; i += 1024) { histD[i] = 0; histS[i] = 0; }
    __syncthreads();
    int base = blockIdx.x * EPB;
    // ---- P1: coalesced read + stage + histograms ----
    for (int i = t; i < EPB; i += 1024) {
        int s = src[base + i], d = dst[base + i];
        est[i] = make_uint2((unsigned int)s, (unsigned int)d);
        atomicAdd(&histD[d >> 8], 1);
        atomicAdd(&histS[s >> 8], 1);
    }
    __syncthreads();
    // ---- global bucket cursors (returning atomics, padded: no line sharing) ----
    for (int i = t; i < NB; i += 1024) {
        int hD = histD[i], hS = histS[i];
        gbD[i] = hD ? atomicAdd(&gcurD[i * GSTRIDE], hD) : 0;
        gbS[i] = hS ? atomicAdd(&gcurS[i * GSTRIDE], hS) : 0;
    }
    // ---- exclusive scans (256-thread pair scan over NB<=512) ----
    // D scan
    if (t < 256) {
        int a = (2 * t < NB) ? histD[2 * t] : 0;
        int b = (2 * t + 1 < NB) ? histD[2 * t + 1] : 0;
        s1[t] = a + b;
    }
    __syncthreads();
    for (int o = 1; o < 256; o <<= 1) {
        int v = 0;
        if (t < 256) v = s1[t] + (t >= o ? s1[t - o] : 0);
        __syncthreads();
        if (t < 256) s1[t] = v;
        __syncthreads();
    }
    if (t < 256) {
        int excl = (t > 0) ? s1[t - 1] : 0;
        if (2 * t < NB) { startD[2 * t] = excl; cursD[2 * t] = excl; }
        if (2 * t + 1 < NB) {
            int e2 = excl + histD[2 * t];
            startD[2 * t + 1] = e2; cursD[2 * t + 1] = e2;
        }
    }
    __syncthreads();
    // S scan
    if (t < 256) {
        int a = (2 * t < NB) ? histS[2 * t] : 0;
        int b = (2 * t + 1 < NB) ? histS[2 * t + 1] : 0;
        s1[t] = a + b;
    }
    __syncthreads();
    for (int o = 1; o < 256; o <<= 1) {
        int v = 0;
        if (t < 256) v = s1[t] + (t >= o ? s1[t - o] : 0);
        __syncthreads();
        if (t < 256) s1[t] = v;
        __syncthreads();
    }
    if (t < 256) {
        int excl = (t > 0) ? s1[t - 1] : 0;
        if (2 * t < NB) { startS[2 * t] = excl; cursS[2 * t] = excl; }
        if (2 * t + 1 < NB) {
            int e2 = excl + histS[2 * t];
            startS[2 * t + 1] = e2; cursS[2 * t + 1] = e2;
        }
    }
    __syncthreads();
    // ---- P2: LDS counting-sort scatter (both keyings, one pass over est) ----
    for (int i = t; i < EPB; i += 1024) {
        uint2 e2 = est[i];
        int s = (int)e2.x, d = (int)e2.y;
        int bd = d >> 8;
        int r = atomicAdd(&cursD[bd], 1);
        sortedPk[r] = ((unsigned int)s << 8) | (unsigned int)(d & 255);
        bIdD[r] = (unsigned short)bd;
        int bs = s >> 8;
        int r2 = atomicAdd(&cursS[bs], 1);
        sByte[r2] = (unsigned char)(s & 255);
        bIdS[r2] = (unsigned short)bs;
    }
    __syncthreads();
    // ---- P3: coalesced write-out (consecutive threads -> consecutive addrs) ----
    for (int i = t; i < EPB; i += 1024) {
        int b = bIdD[i];
        int pos = gbD[b] + (i - startD[b]);
        if (pos < BCAP) ebuf[(size_t)b * BCAP + pos] = sortedPk[i];
        int b2 = bIdS[i];
        int pos2 = gbS[b2] + (i - startS[b2]);
        if (pos2 < BCAP) ebufS[(size_t)b2 * BCAP + pos2] = sByte[i];
    }
}

// ---- fused: blocks 0..NB-1 do per-bucket out-degree histogram -> out_norm;
//      block NB does the exclusive scan of dst-bucket counts -> bbase, row_ptr[N]=E ----
__global__ __launch_bounds__(256) void k_bhist_scan(const unsigned char* __restrict__ ebufS,
                                                    const int* __restrict__ gcurS,
                                                    float* __restrict__ out_norm,
                                                    const int* __restrict__ gcurD,
                                                    int* __restrict__ bbase, int* __restrict__ row_ptr) {
    int t = threadIdx.x;
    if (blockIdx.x < NB) {
        __shared__ int hist[256];
        int b = blockIdx.x;
        hist[t] = 0;
        __syncthreads();
        int ne = min(gcurS[b * GSTRIDE], BCAP);
        const unsigned char* eb = ebufS + (size_t)b * BCAP;
        int nv = ne >> 2;
        const uchar4* ev = (const uchar4*)eb;
        for (int i = t; i < nv; i += 256) {
            uchar4 u = ev[i];
            atomicAdd(&hist[u.x], 1); atomicAdd(&hist[u.y], 1);
            atomicAdd(&hist[u.z], 1); atomicAdd(&hist[u.w], 1);
        }
        for (int i = (nv << 2) + t; i < ne; i += 256) atomicAdd(&hist[eb[i]], 1);
        __syncthreads();
        int node = b * 256 + t;
        if (node < N_NODES) out_norm[node] = hist[t] > 0 ? rsqrtf((float)hist[t]) : 1.0f;
    } else {
        __shared__ int s[NB + 1];
        for (int i = t; i < NB; i += 256) s[i] = min(gcurD[i * GSTRIDE], BCAP);
        __syncthreads();
        if (t == 0) {
            int run = 0;
            for (int b = 0; b < NB; b++) { int v = s[b]; s[b] = run; run += v; }
            s[NB] = run;
        }
        __syncthreads();
        for (int i = t; i < NB + 1; i += 256) bbase[i] = s[i];
        if (t == 0) row_ptr[N_NODES] = s[NB];
    }
}

// ---- merged launch: blocks 0..NB-1 = per-bucket counting sort; blocks NB.. =
// xb = bf16(x*out_norm) streaming scale (12500 blocks). LDS 24.6 KB so the
// streaming blocks get 6 blocks/CU. EXACT R2 version. ----
__global__ __launch_bounds__(256) void k_bsort_xb(const unsigned int* __restrict__ ebuf, const int* __restrict__ gcurD,
                                                  const int* __restrict__ bbase, int* __restrict__ csr_src,
                                                  int* __restrict__ row_ptr, float* __restrict__ in_norm,
                                                  const float* __restrict__ x, const float* __restrict__ out_norm,
                                                  unsigned short* __restrict__ xb) {
    __shared__ int perm[BCAP];          // 20 KB sorted srcs
    __shared__ int hist[256], cursor[256], sa[256], sb[256];
    int t = threadIdx.x;
    if (blockIdx.x >= NB) {             // ---- xb blocks ----
        int tid = (blockIdx.x - NB) * 256 + t;   // 12500 blocks x 256 = N*32 exact
        int row = tid >> 5;
        float4 v = ((const float4*)x)[tid];
        float w = out_norm[row];
        unsigned int lo = (unsigned int)f2bf(v.x * w) | ((unsigned int)f2bf(v.y * w) << 16);
        unsigned int hi = (unsigned int)f2bf(v.z * w) | ((unsigned int)f2bf(v.w * w) << 16);
        ((uint2*)xb)[tid] = make_uint2(lo, hi);
        return;
    }
    int b = blockIdx.x;
    int ne = min(gcurD[b * GSTRIDE], BCAP);
    const unsigned int* eb = ebuf + (size_t)b * BCAP;
    hist[t] = 0;
    __syncthreads();
    for (int i = t; i < ne; i += 256) atomicAdd(&hist[eb[i] & 255u], 1);
    __syncthreads();
    sa[t] = hist[t];
    __syncthreads();
    int* cur = sa; int* nxt = sb;
    for (int o = 1; o < 256; o <<= 1) {
        int v = cur[t] + (t >= o ? cur[t - o] : 0);
        nxt[t] = v;
        __syncthreads();
        int* tmp = cur; cur = nxt; nxt = tmp;
    }
    int ex = cur[t] - hist[t];   // exclusive
    cursor[t] = ex;
    int node = b * 256 + t;
    if (node < N_NODES) {
        row_ptr[node] = bbase[b] + ex;
        in_norm[node] = hist[t] > 0 ? rsqrtf((float)hist[t]) : 1.0f;
    }
    __syncthreads();
    for (int i = t; i < ne; i += 256) {
        unsigned int pk = eb[i];           // L2-warm re-read
        int pos = atomicAdd(&cursor[pk & 255u], 1);
        perm[pos] = (int)(pk >> 8);
    }
    __syncthreads();
    int gb = bbase[b];
    for (int i = t; i < ne; i += 256) csr_src[gb + i] = perm[i];
}

// ---- layer-1 aggregation: wave per dst node, 128 bf16 cols (2/lane), f32 accum ----
// Gather body UNCHANGED (8-deep + 4/2/1 tiers, FETCH 182 MB floor). NEW (R9):
// the node's edge list is register-cached — ONE coalesced csr load per wave
// (cv = csr[e0+lane], 64 indices) + readlane extraction replaces the per-edge
// broadcast csr loads (1.6M VMEM instrs + a load->gather dependence chain).
// DO NOT fuse with gemm12 (R4: occupancy 30%, net -5.6us).
__global__ __launch_bounds__(256) void k_agg1(const unsigned short* __restrict__ xb,
                                              const int* __restrict__ row_ptr, const int* __restrict__ csr,
                                              const float* __restrict__ in_norm,
                                              unsigned short* __restrict__ aggb) {
    int wave = threadIdx.x >> 6, lane = threadIdx.x & 63;
    int d = blockIdx.x * 4 + wave;
    if (d >= N_NODES) return;
    int e0 = __builtin_amdgcn_readfirstlane(row_ptr[d]);
    int e1 = __builtin_amdgcn_readfirstlane(row_ptr[d + 1]);
    int col = lane << 1;
    float accL[8], accH[8];
#pragma unroll
    for (int j = 0; j < 8; j++) { accL[j] = 0.f; accH[j] = 0.f; }
    for (int eb = e0; eb < e1; eb += 64) {      // one iter for deg<=64 (P>64 ~ 0)
        int idx = eb + lane;
        int cv = csr[idx < e1 ? idx : e1 - 1];  // 64 edge indices in registers
        int cnt = min(64, e1 - eb);
        int j = 0;
        for (; j + 8 <= cnt; j += 8) {
            int sI[8];
#pragma unroll
            for (int k = 0; k < 8; k++) sI[k] = __builtin_amdgcn_readlane(cv, j + k);
            unsigned int v[8];
#pragma unroll
            for (int k = 0; k < 8; k++) v[k] = *(const unsigned int*)(xb + (size_t)sI[k] * 128 + col);
#pragma unroll
            for (int k = 0; k < 8; k++) {
                accL[k] += bf2f((unsigned short)(v[k] & 0xffffu));
                accH[k] += bf2f((unsigned short)(v[k] >> 16));
            }
        }
        if (j + 4 <= cnt) {
            int sI[4];
#pragma unroll
            for (int k = 0; k < 4; k++) sI[k] = __builtin_amdgcn_readlane(cv, j + k);
            unsigned int v[4];
#pragma unroll
            for (int k = 0; k < 4; k++) v[k] = *(const unsigned int*)(xb + (size_t)sI[k] * 128 + col);
#pragma unroll
            for (int k = 0; k < 4; k++) {
                accL[k] += bf2f((unsigned short)(v[k] & 0xffffu));
                accH[k] += bf2f((unsigned short)(v[k] >> 16));
            }
            j += 4;
        }
        if (j + 2 <= cnt) {
            int sI[2];
#pragma unroll
            for (int k = 0; k < 2; k++) sI[k] = __builtin_amdgcn_readlane(cv, j + k);
            unsigned int v[2];
#pragma unroll
            for (int k = 0; k < 2; k++) v[k] = *(const unsigned int*)(xb + (size_t)sI[k] * 128 + col);
#pragma unroll
            for (int k = 0; k < 2; k++) {
                accL[k] += bf2f((unsigned short)(v[k] & 0xffffu));
                accH[k] += bf2f((unsigned short)(v[k] >> 16));
            }
            j += 2;
        }
        if (j < cnt) {
            int s = __builtin_amdgcn_readlane(cv, j);
            unsigned int v = *(const unsigned int*)(xb + (size_t)s * 128 + col);
            accL[0] += bf2f((unsigned short)(v & 0xffffu));
            accH[0] += bf2f((unsigned short)(v >> 16));
        }
    }
    float a0 = 0.f, a1 = 0.f;
#pragma unroll
    for (int j = 0; j < 8; j++) { a0 += accL[j]; a1 += accH[j]; }
    float w = in_norm[d];
    unsigned int pk = (unsigned int)f2bf(a0 * w) | ((unsigned int)f2bf(a1 * w) << 16);
    *(unsigned int*)(aggb + (size_t)d * 128 + col) = pk;
}

// ---- fused GEMM1+GEMM2: z = relu(agg1b@W1+b1) -> z_out; zs=bf16(z*out_norm)
// via wave-private LDS tile (stride 132: conflict-free both directions); tb=bf16(zs@W2).
__global__ __launch_bounds__(256) void k_gemm12(const unsigned short* __restrict__ Ab,
                                                const unsigned short* __restrict__ Wp1,
                                                const unsigned short* __restrict__ Wp2,
                                                const float* __restrict__ bias1,
                                                const float* __restrict__ out_norm,
                                                float* __restrict__ z_out,
                                                unsigned short* __restrict__ tb) {
    __shared__ __align__(16) unsigned short lds1[16 * 128 * 8];   // 32 KB packed W1
    __shared__ __align__(16) unsigned short lds2[16 * 64 * 8];    // 16 KB packed W2
    __shared__ __align__(16) unsigned short zt[64 * 132];         // 16.5 KB zs tile
    {
        const uint4* s1 = (const uint4*)Wp1; uint4* d1 = (uint4*)lds1;
        for (int i = threadIdx.x; i < 2048; i += 256) d1[i] = s1[i];
        const uint4* s2 = (const uint4*)Wp2; uint4* d2 = (uint4*)lds2;
        for (int i = threadIdx.x; i < 1024; i += 256) d2[i] = s2[i];
    }
    __syncthreads();
    int wave = threadIdx.x >> 6, lane = threadIdx.x & 63;
    int base = (blockIdx.x * 4 + wave) * 16;
    if (base >= N_NODES) return;
    int m = lane & 15, q = lane >> 4;
    short8 a[4];
#pragma unroll
    for (int t = 0; t < 4; t++) a[t] = *(const short8*)(Ab + (size_t)(base + m) * 128 + t * 32 + q * 8);
    f32x4 acc[8];
#pragma unroll
    for (int c = 0; c < 8; c++) acc[c] = (f32x4)(0.f);
#pragma unroll
    for (int ct = 0; ct < 8; ct++) {
#pragma unroll
        for (int t = 0; t < 4; t++) {
            short8 b = *(const short8*)(lds1 + ((t * 4 + q) * 128 + ct * 16 + m) * 8);
            acc[ct] = __builtin_amdgcn_mfma_f32_16x16x32_bf16(a[t], b, acc[ct], 0, 0, 0);
        }
    }
    float onr[4];
#pragma unroll
    for (int i = 0; i < 4; i++) onr[i] = out_norm[base + q * 4 + i];
#pragma unroll
    for (int ct = 0; ct < 8; ct++) {
        int col = ct * 16 + m;
        float bv = bias1[col];
#pragma unroll
        for (int i = 0; i < 4; i++) {
            int row = base + q * 4 + i;
            float v = acc[ct][i] + bv;
            v = v > 0.f ? v : 0.f;
            z_out[(size_t)row * 128 + col] = v;
            zt[(wave * 16 + q * 4 + i) * 132 + col] = f2bf(v * onr[i]);
        }
    }
    // zt rows wave-private; intra-wave lgkmcnt suffices, no barrier.
    short8 a2[4];
#pragma unroll
    for (int t = 0; t < 4; t++) a2[t] = *(const short8*)(zt + (wave * 16 + m) * 132 + t * 32 + q * 8);
    f32x4 acc2[4];
#pragma unroll
    for (int c = 0; c < 4; c++) acc2[c] = (f32x4)(0.f);
#pragma unroll
    for (int ct = 0; ct < 4; ct++) {
#pragma unroll
        for (int t = 0; t < 4; t++) {
            short8 b = *(const short8*)(lds2 + ((t * 4 + q) * 64 + ct * 16 + m) * 8);
            acc2[ct] = __builtin_amdgcn_mfma_f32_16x16x32_bf16(a2[t], b, acc2[ct], 0, 0, 0);
        }
    }
#pragma unroll
    for (int ct = 0; ct < 4; ct++) {
        int col = ct * 16 + m;
#pragma unroll
        for (int i = 0; i < 4; i++) {
            int row = base + q * 4 + i;
            tb[(size_t)row * 64 + col] = f2bf(acc2[ct][i]);
        }
    }
}

// ---- layer-2 aggregation: 2 edges/instruction (R8) + register-cached edge list
// (R9): one coalesced csr load per wave + readlane, no per-edge broadcast loads.
__global__ __launch_bounds__(256) void k_agg2(const unsigned short* __restrict__ tb,
                                              const int* __restrict__ row_ptr, const int* __restrict__ csr,
                                              const float* __restrict__ in_norm, const float* __restrict__ b2,
                                              float* __restrict__ out_h2) {
    int wave = threadIdx.x >> 6, lane = threadIdx.x & 63;
    int half = lane >> 5, li = lane & 31;
    int d = blockIdx.x * 4 + wave;
    if (d >= N_NODES) return;
    int e0 = __builtin_amdgcn_readfirstlane(row_ptr[d]);
    int e1 = __builtin_amdgcn_readfirstlane(row_ptr[d + 1]);
    int col = li << 1;                 // this lane's 2 cols within its half's edge
    float accA[8], accB[8];
#pragma unroll
    for (int j = 0; j < 8; j++) { accA[j] = 0.f; accB[j] = 0.f; }
    for (int eb = e0; eb < e1; eb += 64) {
        int idx = eb + lane;
        int cv = csr[idx < e1 ? idx : e1 - 1];  // 64 edge indices in registers
        int cnt = min(64, e1 - eb);
        int j = 0;
        for (; j + 16 <= cnt; j += 16) {        // 8 pair-loads = 16 edges
            int sI[8];
#pragma unroll
            for (int k = 0; k < 8; k++) {
                int sA = __builtin_amdgcn_readlane(cv, j + 2 * k);
                int sB = __builtin_amdgcn_readlane(cv, j + 2 * k + 1);
                sI[k] = half ? sB : sA;
            }
            unsigned int v[8];
#pragma unroll
            for (int k = 0; k < 8; k++) v[k] = *(const unsigned int*)(tb + (size_t)sI[k] * 64 + col);
#pragma unroll
            for (int k = 0; k < 8; k++) {
                accA[k] += bf2f((unsigned short)(v[k] & 0xffffu));
                accB[k] += bf2f((unsigned short)(v[k] >> 16));
            }
        }
        if (j + 8 <= cnt) {                     // 4 pairs
            int sI[4];
#pragma unroll
            for (int k = 0; k < 4; k++) {
                int sA = __builtin_amdgcn_readlane(cv, j + 2 * k);
                int sB = __builtin_amdgcn_readlane(cv, j + 2 * k + 1);
                sI[k] = half ? sB : sA;
            }
            unsigned int v[4];
#pragma unroll
            for (int k = 0; k < 4; k++) v[k] = *(const unsigned int*)(tb + (size_t)sI[k] * 64 + col);
#pragma unroll
            for (int k = 0; k < 4; k++) {
                accA[k] += bf2f((unsigned short)(v[k] & 0xffffu));
                accB[k] += bf2f((unsigned short)(v[k] >> 16));
            }
            j += 8;
        }
        if (j + 4 <= cnt) {                     // 2 pairs
            int sI[2];
#pragma unroll
            for (int k = 0; k < 2; k++) {
                int sA = __builtin_amdgcn_readlane(cv, j + 2 * k);
                int sB = __builtin_amdgcn_readlane(cv, j + 2 * k + 1);
                sI[k] = half ? sB : sA;
            }
            unsigned int v[2];
#pragma unroll
            for (int k = 0; k < 2; k++) v[k] = *(const unsigned int*)(tb + (size_t)sI[k] * 64 + col);
#pragma unroll
            for (int k = 0; k < 2; k++) {
                accA[k] += bf2f((unsigned short)(v[k] & 0xffffu));
                accB[k] += bf2f((unsigned short)(v[k] >> 16));
            }
            j += 4;
        }
        if (j + 2 <= cnt) {                     // 1 pair
            int sA = __builtin_amdgcn_readlane(cv, j);
            int sB = __builtin_amdgcn_readlane(cv, j + 1);
            int s = half ? sB : sA;
            unsigned int v = *(const unsigned int*)(tb + (size_t)s * 64 + col);
            accA[0] += bf2f((unsigned short)(v & 0xffffu));
            accB[0] += bf2f((unsigned short)(v >> 16));
            j += 2;
        }
        if (j < cnt) {                          // odd edge: half 0 only
            int s = __builtin_amdgcn_readlane(cv, j);
            unsigned int v = *(const unsigned int*)(tb + (size_t)s * 64 + col);
            if (half == 0) {
                accA[0] += bf2f((unsigned short)(v & 0xffffu));
                accB[0] += bf2f((unsigned short)(v >> 16));
            }
        }
    }
    float a0 = 0.f, a1 = 0.f;
#pragma unroll
    for (int j = 0; j < 8; j++) { a0 += accA[j]; a1 += accB[j]; }
    a0 += __shfl_xor(a0, 32);          // combine the two halves' edge subsets
    a1 += __shfl_xor(a1, 32);
    if (half == 0) {
        float w = in_norm[d];
        float2 r;
        r.x = a0 * w + b2[col];
        r.y = a1 * w + b2[col + 1];
        *(float2*)(out_h2 + (size_t)d * 64 + col) = r;
    }
}

extern "C" void kernel_launch(void* const* d_in, const int* in_sizes, int n_in,
                              void* d_out, int out_size, void* d_ws, size_t ws_size,
                              hipStream_t stream) {
    const float* x   = (const float*)d_in[0];
    const int*   src = (const int*)d_in[1];
    const int*   dst = (const int*)d_in[2];
    const float* W1  = (const float*)d_in[3];
    const float* b1  = (const float*)d_in[4];
    const float* W2  = (const float*)d_in[5];
    const float* b2  = (const float*)d_in[6];
    float* out_h2 = (float*)d_out;                     // [N,64]
    float* out_z  = (float*)d_out + N_NODES * 64;      // [N,128]

    char* ws = (char*)d_ws;
    size_t off = 0;
    auto alloc = [&](size_t bytes) -> char* {
        char* p = ws + off;
        off = (off + bytes + 255) & ~(size_t)255;
        return p;
    };
    int* gcurD    = (int*)alloc(NB * GSTRIDE * 4);     // padded: 1 counter / 64B line
    int* gcurS    = (int*)alloc(NB * GSTRIDE * 4);     // contiguous with gcurD: one memset
    int* bbase    = (int*)alloc((NB + 1) * 4);
    int* row_ptr  = (int*)alloc((N_NODES + 1) * 4);
    float* out_norm = (float*)alloc(N_NODES * 4);
    float* in_norm  = (float*)alloc(N_NODES * 4);
    unsigned int* ebuf = (unsigned int*)alloc((size_t)NB * BCAP * 4);        // 8.0 MB
    unsigned char* ebufS = (unsigned char*)alloc((size_t)NB * BCAP);         // 2.0 MB
    int* csr_src  = (int*)alloc((size_t)N_EDGES * 4);
    unsigned short* Wp1 = (unsigned short*)alloc(2048 * 8 * 2);
    unsigned short* Wp2 = (unsigned short*)alloc(1024 * 8 * 2);
    unsigned short* xb    = (unsigned short*)alloc((size_t)N_NODES * 128 * 2);
    unsigned short* agg1b = (unsigned short*)alloc((size_t)N_NODES * 128 * 2);
    unsigned short* tb    = (unsigned short*)alloc((size_t)N_NODES * 64 * 2);  // bf16 t
    (void)ws_size; (void)in_sizes; (void)n_in; (void)out_size;

    const size_t gcur_pad = ((size_t)(NB * GSTRIDE * 4) + 255) & ~(size_t)255;
    hipMemsetAsync(gcurD, 0, gcur_pad + (size_t)NB * GSTRIDE * 4, stream);   // covers gcurD+gcurS

    const int GD_AGG = (N_NODES + 3) / 4;       // 25000
    const int GD_GEMM = (N_NODES / 16 + 3) / 4; // 1563
    const int GD_XB = N_NODES * 32 / 256;       // 12500

    k_part<<<PART_BLOCKS + 3, 1024, 0, stream>>>(src, dst, gcurD, gcurS, ebuf, ebufS, W1, W2, Wp1, Wp2);
    k_bhist_scan<<<NB + 1, 256, 0, stream>>>(ebufS, gcurS, out_norm, gcurD, bbase, row_ptr);
    k_bsort_xb<<<NB + GD_XB, 256, 0, stream>>>(ebuf, gcurD, bbase, csr_src, row_ptr, in_norm, x, out_norm, xb);
    k_agg1<<<GD_AGG, 256, 0, stream>>>(xb, row_ptr, csr_src, in_norm, agg1b);
    k_gemm12<<<GD_GEMM, 256, 0, stream>>>(agg1b, Wp1, Wp2, b1, out_norm, out_z, tb);
    k_agg2<<<GD_AGG, 256, 0, stream>>>(tb, row_ptr, csr_src, in_norm, b2, out_h2);
}

// Round 10
// 276.944 us; speedup vs baseline: 1.0115x; 1.0115x over previous
//
#include <hip/hip_runtime.h>

#define N_NODES 100000
#define N_EDGES 1600000
#define NB 391          // coarse buckets of 256 nodes
#define BCAP 5120       // per-bucket capacity (expected 4092, 16-sigma headroom)
#define PART_BLOCKS 250
#define EPB 6400        // edges per partition block (250*6400 = 1.6M exact)
#define GSTRIDE 16      // global cursor pad: 1 counter per 64B line (atomic channel parallelism)

typedef __attribute__((ext_vector_type(8))) short short8;   // 8 bf16 (4 VGPR) MFMA frag
typedef __attribute__((ext_vector_type(4))) float f32x4;    // MFMA accumulator

__device__ inline unsigned short f2bf(float f) {
    unsigned int u = __builtin_bit_cast(unsigned int, f);
    u += 0x7fffu + ((u >> 16) & 1u);   // round-to-nearest-even
    return (unsigned short)(u >> 16);
}
__device__ inline float bf2f(unsigned short h) {
    unsigned int u = ((unsigned int)h) << 16;
    return __builtin_bit_cast(float, u);
}

// ---- partition (blocks 0..249, 1024 thr): LDS counting-sort -> COALESCED writes.
//      (R7: 42 -> ~33 us; write-amplification halved. Residual cost = LDS atomic
//      scatter + barrier chain.) Failed variants (do not retry): 800 blocks (R1),
//      global degS atomics (R3), TLP beyond 16 waves (R6 flat).
//      blocks 250..252: pack W1/W2 bf16 B-fragments. ----
__global__ __launch_bounds__(1024) void k_part(const int* __restrict__ src, const int* __restrict__ dst,
                                               int* __restrict__ gcurD, int* __restrict__ gcurS,
                                               unsigned int* __restrict__ ebuf,
                                               unsigned char* __restrict__ ebufS,
                                               const float* __restrict__ W1, const float* __restrict__ W2,
                                               unsigned short* __restrict__ Wp1, unsigned short* __restrict__ Wp2) {
    if (blockIdx.x >= PART_BLOCKS) {          // ---- pack_w blocks ----
        int i = (blockIdx.x - PART_BLOCKS) * 1024 + threadIdx.x;   // 3072 total
        if (i < 2048) {                       // W1: 16 kq x 128 c
            int kq = i >> 7, c = i & 127;
#pragma unroll
            for (int j = 0; j < 8; j++) Wp1[i * 8 + j] = f2bf(W1[(kq * 8 + j) * 128 + c]);
        } else if (i < 3072) {                // W2: 16 kq x 64 c
            int i2 = i - 2048;
            int kq = i2 >> 6, c = i2 & 63;
#pragma unroll
            for (int j = 0; j < 8; j++) Wp2[i2 * 8 + j] = f2bf(W2[(kq * 8 + j) * 64 + c]);
        }
        return;
    }
    __shared__ uint2 est[EPB];                       // 51.2 KB staged (src,dst)
    __shared__ unsigned int sortedPk[EPB];           // 25.6 KB dst-sorted records
    __shared__ unsigned short bIdD[EPB];             // 12.8 KB bucket id per slot
    __shared__ unsigned short bIdS[EPB];             // 12.8 KB (src keying)
    __shared__ unsigned char sByte[EPB];             //  6.4 KB src-sorted bytes
    __shared__ int histD[NB], histS[NB], startD[NB], startS[NB];
    __shared__ int gbD[NB], gbS[NB], cursD[NB], cursS[NB];
    __shared__ int s1[256];
    int t = threadIdx.x;
    for (int i = t; i < NB; i += 1024) { histD[i] = 0; histS[i] = 0; }
    __syncthreads();
    int base = blockIdx.x * EPB;
    // ---- P1: coalesced read + stage + histograms ----
    for (int i = t; i < EPB; i += 1024) {
        int s = src[base + i], d = dst[base + i];
        est[i] = make_uint2((unsigned int)s, (unsigned int)d);
        atomicAdd(&histD[d >> 8], 1);
        atomicAdd(&histS[s >> 8], 1);
    }
    __syncthreads();
    // ---- global bucket cursors (returning atomics, padded: no line sharing) ----
    for (int i = t; i < NB; i += 1024) {
        int hD = histD[i], hS = histS[i];
        gbD[i] = hD ? atomicAdd(&gcurD[i * GSTRIDE], hD) : 0;
        gbS[i] = hS ? atomicAdd(&gcurS[i * GSTRIDE], hS) : 0;
    }
    // ---- exclusive scans (256-thread pair scan over NB<=512) ----
    // D scan
    if (t < 256) {
        int a = (2 * t < NB) ? histD[2 * t] : 0;
        int b = (2 * t + 1 < NB) ? histD[2 * t + 1] : 0;
        s1[t] = a + b;
    }
    __syncthreads();
    for (int o = 1; o < 256; o <<= 1) {
        int v = 0;
        if (t < 256) v = s1[t] + (t >= o ? s1[t - o] : 0);
        __syncthreads();
        if (t < 256) s1[t] = v;
        __syncthreads();
    }
    if (t < 256) {
        int excl = (t > 0) ? s1[t - 1] : 0;
        if (2 * t < NB) { startD[2 * t] = excl; cursD[2 * t] = excl; }
        if (2 * t + 1 < NB) {
            int e2 = excl + histD[2 * t];
            startD[2 * t + 1] = e2; cursD[2 * t + 1] = e2;
        }
    }
    __syncthreads();
    // S scan
    if (t < 256) {
        int a = (2 * t < NB) ? histS[2 * t] : 0;
        int b = (2 * t + 1 < NB) ? histS[2 * t + 1] : 0;
        s1[t] = a + b;
    }
    __syncthreads();
    for (int o = 1; o < 256; o <<= 1) {
        int v = 0;
        if (t < 256) v = s1[t] + (t >= o ? s1[t - o] : 0);
        __syncthreads();
        if (t < 256) s1[t] = v;
        __syncthreads();
    }
    if (t < 256) {
        int excl = (t > 0) ? s1[t - 1] : 0;
        if (2 * t < NB) { startS[2 * t] = excl; cursS[2 * t] = excl; }
        if (2 * t + 1 < NB) {
            int e2 = excl + histS[2 * t];
            startS[2 * t + 1] = e2; cursS[2 * t + 1] = e2;
        }
    }
    __syncthreads();
    // ---- P2: LDS counting-sort scatter (both keyings, one pass over est) ----
    for (int i = t; i < EPB; i += 1024) {
        uint2 e2 = est[i];
        int s = (int)e2.x, d = (int)e2.y;
        int bd = d >> 8;
        int r = atomicAdd(&cursD[bd], 1);
        sortedPk[r] = ((unsigned int)s << 8) | (unsigned int)(d & 255);
        bIdD[r] = (unsigned short)bd;
        int bs = s >> 8;
        int r2 = atomicAdd(&cursS[bs], 1);
        sByte[r2] = (unsigned char)(s & 255);
        bIdS[r2] = (unsigned short)bs;
    }
    __syncthreads();
    // ---- P3: coalesced write-out (consecutive threads -> consecutive addrs) ----
    for (int i = t; i < EPB; i += 1024) {
        int b = bIdD[i];
        int pos = gbD[b] + (i - startD[b]);
        if (pos < BCAP) ebuf[(size_t)b * BCAP + pos] = sortedPk[i];
        int b2 = bIdS[i];
        int pos2 = gbS[b2] + (i - startS[b2]);
        if (pos2 < BCAP) ebufS[(size_t)b2 * BCAP + pos2] = sByte[i];
    }
}

// ---- fused: blocks 0..NB-1 do per-bucket out-degree histogram -> out_norm;
//      block NB does the exclusive scan of dst-bucket counts -> bbase, row_ptr[N]=E ----
__global__ __launch_bounds__(256) void k_bhist_scan(const unsigned char* __restrict__ ebufS,
                                                    const int* __restrict__ gcurS,
                                                    float* __restrict__ out_norm,
                                                    const int* __restrict__ gcurD,
                                                    int* __restrict__ bbase, int* __restrict__ row_ptr) {
    int t = threadIdx.x;
    if (blockIdx.x < NB) {
        __shared__ int hist[256];
        int b = blockIdx.x;
        hist[t] = 0;
        __syncthreads();
        int ne = min(gcurS[b * GSTRIDE], BCAP);
        const unsigned char* eb = ebufS + (size_t)b * BCAP;
        int nv = ne >> 2;
        const uchar4* ev = (const uchar4*)eb;
        for (int i = t; i < nv; i += 256) {
            uchar4 u = ev[i];
            atomicAdd(&hist[u.x], 1); atomicAdd(&hist[u.y], 1);
            atomicAdd(&hist[u.z], 1); atomicAdd(&hist[u.w], 1);
        }
        for (int i = (nv << 2) + t; i < ne; i += 256) atomicAdd(&hist[eb[i]], 1);
        __syncthreads();
        int node = b * 256 + t;
        if (node < N_NODES) out_norm[node] = hist[t] > 0 ? rsqrtf((float)hist[t]) : 1.0f;
    } else {
        __shared__ int s[NB + 1];
        for (int i = t; i < NB; i += 256) s[i] = min(gcurD[i * GSTRIDE], BCAP);
        __syncthreads();
        if (t == 0) {
            int run = 0;
            for (int b = 0; b < NB; b++) { int v = s[b]; s[b] = run; run += v; }
            s[NB] = run;
        }
        __syncthreads();
        for (int i = t; i < NB + 1; i += 256) bbase[i] = s[i];
        if (t == 0) row_ptr[N_NODES] = s[NB];
    }
}

// ---- merged launch: blocks 0..NB-1 = per-bucket counting sort; blocks NB.. =
// xb = bf16(x*out_norm) streaming scale (12500 blocks). LDS 24.6 KB so the
// streaming blocks get 6 blocks/CU. EXACT R2 version. ----
__global__ __launch_bounds__(256) void k_bsort_xb(const unsigned int* __restrict__ ebuf, const int* __restrict__ gcurD,
                                                  const int* __restrict__ bbase, int* __restrict__ csr_src,
                                                  int* __restrict__ row_ptr, float* __restrict__ in_norm,
                                                  const float* __restrict__ x, const float* __restrict__ out_norm,
                                                  unsigned short* __restrict__ xb) {
    __shared__ int perm[BCAP];          // 20 KB sorted srcs
    __shared__ int hist[256], cursor[256], sa[256], sb[256];
    int t = threadIdx.x;
    if (blockIdx.x >= NB) {             // ---- xb blocks ----
        int tid = (blockIdx.x - NB) * 256 + t;   // 12500 blocks x 256 = N*32 exact
        int row = tid >> 5;
        float4 v = ((const float4*)x)[tid];
        float w = out_norm[row];
        unsigned int lo = (unsigned int)f2bf(v.x * w) | ((unsigned int)f2bf(v.y * w) << 16);
        unsigned int hi = (unsigned int)f2bf(v.z * w) | ((unsigned int)f2bf(v.w * w) << 16);
        ((uint2*)xb)[tid] = make_uint2(lo, hi);
        return;
    }
    int b = blockIdx.x;
    int ne = min(gcurD[b * GSTRIDE], BCAP);
    const unsigned int* eb = ebuf + (size_t)b * BCAP;
    hist[t] = 0;
    __syncthreads();
    for (int i = t; i < ne; i += 256) atomicAdd(&hist[eb[i] & 255u], 1);
    __syncthreads();
    sa[t] = hist[t];
    __syncthreads();
    int* cur = sa; int* nxt = sb;
    for (int o = 1; o < 256; o <<= 1) {
        int v = cur[t] + (t >= o ? cur[t - o] : 0);
        nxt[t] = v;
        __syncthreads();
        int* tmp = cur; cur = nxt; nxt = tmp;
    }
    int ex = cur[t] - hist[t];   // exclusive
    cursor[t] = ex;
    int node = b * 256 + t;
    if (node < N_NODES) {
        row_ptr[node] = bbase[b] + ex;
        in_norm[node] = hist[t] > 0 ? rsqrtf((float)hist[t]) : 1.0f;
    }
    __syncthreads();
    for (int i = t; i < ne; i += 256) {
        unsigned int pk = eb[i];           // L2-warm re-read
        int pos = atomicAdd(&cursor[pk & 255u], 1);
        perm[pos] = (int)(pk >> 8);
    }
    __syncthreads();
    int gb = bbase[b];
    for (int i = t; i < ne; i += 256) csr_src[gb + i] = perm[i];
}

// ---- layer-1 aggregation: wave per dst node, 128 bf16 cols (2/lane), f32 accum ----
// CLOSED (R9): delivered 3.65 TB/s is the L2-miss/L3 random-line ceiling for this
// gather — removing all 1.6M csr broadcast loads (readlane cache) left dur
// unchanged (FETCH -3 MB as predicted, VALUBusy 33->41%, dur 57.9 both ways).
// 8-deep + 4/2/1 tiers, FETCH 182 MB floor. DO NOT fuse with gemm12 (R4).
__global__ __launch_bounds__(256) void k_agg1(const unsigned short* __restrict__ xb,
                                              const int* __restrict__ row_ptr, const int* __restrict__ csr,
                                              const float* __restrict__ in_norm,
                                              unsigned short* __restrict__ aggb) {
    int wave = threadIdx.x >> 6, lane = threadIdx.x & 63;
    int d = blockIdx.x * 4 + wave;
    if (d >= N_NODES) return;
    int e0 = __builtin_amdgcn_readfirstlane(row_ptr[d]);
    int e1 = __builtin_amdgcn_readfirstlane(row_ptr[d + 1]);
    int col = lane << 1;
    float accL[8], accH[8];
#pragma unroll
    for (int j = 0; j < 8; j++) { accL[j] = 0.f; accH[j] = 0.f; }
    int e = e0;
    for (; e + 8 <= e1; e += 8) {
        int sI[8];
#pragma unroll
        for (int j = 0; j < 8; j++) sI[j] = __builtin_amdgcn_readfirstlane(csr[e + j]);
        unsigned int v[8];
#pragma unroll
        for (int j = 0; j < 8; j++) v[j] = *(const unsigned int*)(xb + (size_t)sI[j] * 128 + col);
#pragma unroll
        for (int j = 0; j < 8; j++) {
            accL[j] += bf2f((unsigned short)(v[j] & 0xffffu));
            accH[j] += bf2f((unsigned short)(v[j] >> 16));
        }
    }
    if (e + 4 <= e1) {
        int sI[4];
#pragma unroll
        for (int j = 0; j < 4; j++) sI[j] = __builtin_amdgcn_readfirstlane(csr[e + j]);
        unsigned int v[4];
#pragma unroll
        for (int j = 0; j < 4; j++) v[j] = *(const unsigned int*)(xb + (size_t)sI[j] * 128 + col);
#pragma unroll
        for (int j = 0; j < 4; j++) {
            accL[j] += bf2f((unsigned short)(v[j] & 0xffffu));
            accH[j] += bf2f((unsigned short)(v[j] >> 16));
        }
        e += 4;
    }
    if (e + 2 <= e1) {
        int sI[2];
#pragma unroll
        for (int j = 0; j < 2; j++) sI[j] = __builtin_amdgcn_readfirstlane(csr[e + j]);
        unsigned int v[2];
#pragma unroll
        for (int j = 0; j < 2; j++) v[j] = *(const unsigned int*)(xb + (size_t)sI[j] * 128 + col);
#pragma unroll
        for (int j = 0; j < 2; j++) {
            accL[j] += bf2f((unsigned short)(v[j] & 0xffffu));
            accH[j] += bf2f((unsigned short)(v[j] >> 16));
        }
        e += 2;
    }
    if (e < e1) {
        int s = __builtin_amdgcn_readfirstlane(csr[e]);
        unsigned int v = *(const unsigned int*)(xb + (size_t)s * 128 + col);
        accL[0] += bf2f((unsigned short)(v & 0xffffu));
        accH[0] += bf2f((unsigned short)(v >> 16));
    }
    float a0 = 0.f, a1 = 0.f;
#pragma unroll
    for (int j = 0; j < 8; j++) { a0 += accL[j]; a1 += accH[j]; }
    float w = in_norm[d];
    unsigned int pk = (unsigned int)f2bf(a0 * w) | ((unsigned int)f2bf(a1 * w) << 16);
    *(unsigned int*)(aggb + (size_t)d * 128 + col) = pk;
}

// ---- fused GEMM1+GEMM2 (R10): W1/W2 B-fragments read DIRECTLY from L2 — the
// 48 KB weight set is L2-resident and the LDS staging (48 KB/block) capped the
// kernel at 2 blocks/CU. LDS now = zt only (16.5 KB) -> ~6 blocks/CU (grid-
// limited), 3x the latency hiding for the A-row stream. Mechanism validated by
// R4's agg1g (direct-L2 weights fed MFMA fine; its failure was the gather
// phase, absent here). zt stride 132: conflict-free both directions. ----
__global__ __launch_bounds__(256) void k_gemm12(const unsigned short* __restrict__ Ab,
                                                const unsigned short* __restrict__ Wp1,
                                                const unsigned short* __restrict__ Wp2,
                                                const float* __restrict__ bias1,
                                                const float* __restrict__ out_norm,
                                                float* __restrict__ z_out,
                                                unsigned short* __restrict__ tb) {
    __shared__ __align__(16) unsigned short zt[64 * 132];         // 16.5 KB zs tile
    int wave = threadIdx.x >> 6, lane = threadIdx.x & 63;
    int base = (blockIdx.x * 4 + wave) * 16;
    if (base >= N_NODES) return;
    int m = lane & 15, q = lane >> 4;
    short8 a[4];
#pragma unroll
    for (int t = 0; t < 4; t++) a[t] = *(const short8*)(Ab + (size_t)(base + m) * 128 + t * 32 + q * 8);
    f32x4 acc[8];
#pragma unroll
    for (int c = 0; c < 8; c++) acc[c] = (f32x4)(0.f);
#pragma unroll
    for (int ct = 0; ct < 8; ct++) {
#pragma unroll
        for (int t = 0; t < 4; t++) {
            short8 b = *(const short8*)(Wp1 + ((size_t)((t * 4 + q) * 128 + ct * 16 + m)) * 8);
            acc[ct] = __builtin_amdgcn_mfma_f32_16x16x32_bf16(a[t], b, acc[ct], 0, 0, 0);
        }
    }
    float onr[4];
#pragma unroll
    for (int i = 0; i < 4; i++) onr[i] = out_norm[base + q * 4 + i];
#pragma unroll
    for (int ct = 0; ct < 8; ct++) {
        int col = ct * 16 + m;
        float bv = bias1[col];
#pragma unroll
        for (int i = 0; i < 4; i++) {
            int row = base + q * 4 + i;
            float v = acc[ct][i] + bv;
            v = v > 0.f ? v : 0.f;
            z_out[(size_t)row * 128 + col] = v;
            zt[(wave * 16 + q * 4 + i) * 132 + col] = f2bf(v * onr[i]);
        }
    }
    // zt rows wave-private; intra-wave lgkmcnt suffices, no barrier.
    short8 a2[4];
#pragma unroll
    for (int t = 0; t < 4; t++) a2[t] = *(const short8*)(zt + (wave * 16 + m) * 132 + t * 32 + q * 8);
    f32x4 acc2[4];
#pragma unroll
    for (int c = 0; c < 4; c++) acc2[c] = (f32x4)(0.f);
#pragma unroll
    for (int ct = 0; ct < 4; ct++) {
#pragma unroll
        for (int t = 0; t < 4; t++) {
            short8 b = *(const short8*)(Wp2 + ((size_t)((t * 4 + q) * 64 + ct * 16 + m)) * 8);
            acc2[ct] = __builtin_amdgcn_mfma_f32_16x16x32_bf16(a2[t], b, acc2[ct], 0, 0, 0);
        }
    }
#pragma unroll
    for (int ct = 0; ct < 4; ct++) {
        int col = ct * 16 + m;
#pragma unroll
        for (int i = 0; i < 4; i++) {
            int row = base + q * 4 + i;
            tb[(size_t)row * 64 + col] = f2bf(acc2[ct][i]);
        }
    }
}

// ---- layer-2 aggregation: TWO edges per wave-instruction (R8). CLOSED with
// agg1 (R8 pairing null, R9 readlane null -> L3 random-line BW-bound). ----
__global__ __launch_bounds__(256) void k_agg2(const unsigned short* __restrict__ tb,
                                              const int* __restrict__ row_ptr, const int* __restrict__ csr,
                                              const float* __restrict__ in_norm, const float* __restrict__ b2,
                                              float* __restrict__ out_h2) {
    int wave = threadIdx.x >> 6, lane = threadIdx.x & 63;
    int half = lane >> 5, li = lane & 31;
    int d = blockIdx.x * 4 + wave;
    if (d >= N_NODES) return;
    int e0 = __builtin_amdgcn_readfirstlane(row_ptr[d]);
    int e1 = __builtin_amdgcn_readfirstlane(row_ptr[d + 1]);
    int col = li << 1;                 // this lane's 2 cols within its half's edge
    float accA[8], accB[8];
#pragma unroll
    for (int j = 0; j < 8; j++) { accA[j] = 0.f; accB[j] = 0.f; }
    int e = e0;
    for (; e + 16 <= e1; e += 16) {    // 8 pair-loads = 16 edges
        int sI[8];
#pragma unroll
        for (int j = 0; j < 8; j++) {
            int sA = __builtin_amdgcn_readfirstlane(csr[e + 2 * j]);
            int sB = __builtin_amdgcn_readfirstlane(csr[e + 2 * j + 1]);
            sI[j] = half ? sB : sA;
        }
        unsigned int v[8];
#pragma unroll
        for (int j = 0; j < 8; j++) v[j] = *(const unsigned int*)(tb + (size_t)sI[j] * 64 + col);
#pragma unroll
        for (int j = 0; j < 8; j++) {
            accA[j] += bf2f((unsigned short)(v[j] & 0xffffu));
            accB[j] += bf2f((unsigned short)(v[j] >> 16));
        }
    }
    if (e + 8 <= e1) {                 // 4 pairs
        int sI[4];
#pragma unroll
        for (int j = 0; j < 4; j++) {
            int sA = __builtin_amdgcn_readfirstlane(csr[e + 2 * j]);
            int sB = __builtin_amdgcn_readfirstlane(csr[e + 2 * j + 1]);
            sI[j] = half ? sB : sA;
        }
        unsigned int v[4];
#pragma unroll
        for (int j = 0; j < 4; j++) v[j] = *(const unsigned int*)(tb + (size_t)sI[j] * 64 + col);
#pragma unroll
        for (int j = 0; j < 4; j++) {
            accA[j] += bf2f((unsigned short)(v[j] & 0xffffu));
            accB[j] += bf2f((unsigned short)(v[j] >> 16));
        }
        e += 8;
    }
    if (e + 4 <= e1) {                 // 2 pairs
        int sI[2];
#pragma unroll
        for (int j = 0; j < 2; j++) {
            int sA = __builtin_amdgcn_readfirstlane(csr[e + 2 * j]);
            int sB = __builtin_amdgcn_readfirstlane(csr[e + 2 * j + 1]);
            sI[j] = half ? sB : sA;
        }
        unsigned int v[2];
#pragma unroll
        for (int j = 0; j < 2; j++) v[j] = *(const unsigned int*)(tb + (size_t)sI[j] * 64 + col);
#pragma unroll
        for (int j = 0; j < 2; j++) {
            accA[j] += bf2f((unsigned short)(v[j] & 0xffffu));
            accB[j] += bf2f((unsigned short)(v[j] >> 16));
        }
        e += 2 * 2;
    }
    if (e + 2 <= e1) {                 // 1 pair
        int sA = __builtin_amdgcn_readfirstlane(csr[e]);
        int sB = __builtin_amdgcn_readfirstlane(csr[e + 1]);
        int s = half ? sB : sA;
        unsigned int v = *(const unsigned int*)(tb + (size_t)s * 64 + col);
        accA[0] += bf2f((unsigned short)(v & 0xffffu));
        accB[0] += bf2f((unsigned short)(v >> 16));
        e += 2;
    }
    if (e < e1) {                      // odd edge: half 0 only (avoid double count)
        int s = __builtin_amdgcn_readfirstlane(csr[e]);
        unsigned int v = *(const unsigned int*)(tb + (size_t)s * 64 + col);
        if (half == 0) {
            accA[0] += bf2f((unsigned short)(v & 0xffffu));
            accB[0] += bf2f((unsigned short)(v >> 16));
        }
    }
    float a0 = 0.f, a1 = 0.f;
#pragma unroll
    for (int j = 0; j < 8; j++) { a0 += accA[j]; a1 += accB[j]; }
    a0 += __shfl_xor(a0, 32);          // combine the two halves' edge subsets
    a1 += __shfl_xor(a1, 32);
    if (half == 0) {
        float w = in_norm[d];
        float2 r;
        r.x = a0 * w + b2[col];
        r.y = a1 * w + b2[col + 1];
        *(float2*)(out_h2 + (size_t)d * 64 + col) = r;
    }
}

extern "C" void kernel_launch(void* const* d_in, const int* in_sizes, int n_in,
                              void* d_out, int out_size, void* d_ws, size_t ws_size,
                              hipStream_t stream) {
    const float* x   = (const float*)d_in[0];
    const int*   src = (const int*)d_in[1];
    const int*   dst = (const int*)d_in[2];
    const float* W1  = (const float*)d_in[3];
    const float* b1  = (const float*)d_in[4];
    const float* W2  = (const float*)d_in[5];
    const float* b2  = (const float*)d_in[6];
    float* out_h2 = (float*)d_out;                     // [N,64]
    float* out_z  = (float*)d_out + N_NODES * 64;      // [N,128]

    char* ws = (char*)d_ws;
    size_t off = 0;
    auto alloc = [&](size_t bytes) -> char* {
        char* p = ws + off;
        off = (off + bytes + 255) & ~(size_t)255;
        return p;
    };
    int* gcurD    = (int*)alloc(NB * GSTRIDE * 4);     // padded: 1 counter / 64B line
    int* gcurS    = (int*)alloc(NB * GSTRIDE * 4);     // contiguous with gcurD: one memset
    int* bbase    = (int*)alloc((NB + 1) * 4);
    int* row_ptr  = (int*)alloc((N_NODES + 1) * 4);
    float* out_norm = (float*)alloc(N_NODES * 4);
    float* in_norm  = (float*)alloc(N_NODES * 4);
    unsigned int* ebuf = (unsigned int*)alloc((size_t)NB * BCAP * 4);        // 8.0 MB
    unsigned char* ebufS = (unsigned char*)alloc((size_t)NB * BCAP);         // 2.0 MB
    int* csr_src  = (int*)alloc((size_t)N_EDGES * 4);
    unsigned short* Wp1 = (unsigned short*)alloc(2048 * 8 * 2);
    unsigned short* Wp2 = (unsigned short*)alloc(1024 * 8 * 2);
    unsigned short* xb    = (unsigned short*)alloc((size_t)N_NODES * 128 * 2);
    unsigned short* agg1b = (unsigned short*)alloc((size_t)N_NODES * 128 * 2);
    unsigned short* tb    = (unsigned short*)alloc((size_t)N_NODES * 64 * 2);  // bf16 t
    (void)ws_size; (void)in_sizes; (void)n_in; (void)out_size;

    const size_t gcur_pad = ((size_t)(NB * GSTRIDE * 4) + 255) & ~(size_t)255;
    hipMemsetAsync(gcurD, 0, gcur_pad + (size_t)NB * GSTRIDE * 4, stream);   // covers gcurD+gcurS

    const int GD_AGG = (N_NODES + 3) / 4;       // 25000
    const int GD_GEMM = (N_NODES / 16 + 3) / 4; // 1563
    const int GD_XB = N_NODES * 32 / 256;       // 12500

    k_part<<<PART_BLOCKS + 3, 1024, 0, stream>>>(src, dst, gcurD, gcurS, ebuf, ebufS, W1, W2, Wp1, Wp2);
    k_bhist_scan<<<NB + 1, 256, 0, stream>>>(ebufS, gcurS, out_norm, gcurD, bbase, row_ptr);
    k_bsort_xb<<<NB + GD_XB, 256, 0, stream>>>(ebuf, gcurD, bbase, csr_src, row_ptr, in_norm, x, out_norm, xb);
    k_agg1<<<GD_AGG, 256, 0, stream>>>(xb, row_ptr, csr_src, in_norm, agg1b);
    k_gemm12<<<GD_GEMM, 256, 0, stream>>>(agg1b, Wp1, Wp2, b1, out_norm, out_z, tb);
    k_agg2<<<GD_AGG, 256, 0, stream>>>(tb, row_ptr, csr_src, in_norm, b2, out_h2);
}

// Round 12
// 272.322 us; speedup vs baseline: 1.0287x; 1.0170x over previous
//
#include <hip/hip_runtime.h>

#define N_NODES 100000
#define N_EDGES 1600000
#define NB 391          // coarse buckets of 256 nodes
#define BCAP 5120       // per-bucket capacity (expected 4092, 16-sigma headroom)
#define PART_BLOCKS 250
#define EPB 6400        // edges per partition block (250*6400 = 1.6M exact)
#define GSTRIDE 16      // global cursor pad: 1 counter per 64B line (atomic channel parallelism)

typedef __attribute__((ext_vector_type(8))) short short8;   // 8 bf16 (4 VGPR) MFMA frag
typedef __attribute__((ext_vector_type(4))) float f32x4;    // MFMA accumulator

__device__ inline unsigned short f2bf(float f) {
    unsigned int u = __builtin_bit_cast(unsigned int, f);
    u += 0x7fffu + ((u >> 16) & 1u);   // round-to-nearest-even
    return (unsigned short)(u >> 16);
}
__device__ inline float bf2f(unsigned short h) {
    unsigned int u = ((unsigned int)h) << 16;
    return __builtin_bit_cast(float, u);
}

// ---- partition (blocks 0..249, 1024 thr): LDS counting-sort -> COALESCED writes.
//      (R7: 42 -> ~33 us.) Failed variants (do not retry): 800 blocks (R1),
//      global degS atomics (R3), TLP beyond 16 waves (R6 flat).
//      blocks 250..252: pack W1/W2 bf16 B-fragments. ----
__global__ __launch_bounds__(1024) void k_part(const int* __restrict__ src, const int* __restrict__ dst,
                                               int* __restrict__ gcurD, int* __restrict__ gcurS,
                                               unsigned int* __restrict__ ebuf,
                                               unsigned char* __restrict__ ebufS,
                                               const float* __restrict__ W1, const float* __restrict__ W2,
                                               unsigned short* __restrict__ Wp1, unsigned short* __restrict__ Wp2) {
    if (blockIdx.x >= PART_BLOCKS) {          // ---- pack_w blocks ----
        int i = (blockIdx.x - PART_BLOCKS) * 1024 + threadIdx.x;   // 3072 total
        if (i < 2048) {                       // W1: 16 kq x 128 c
            int kq = i >> 7, c = i & 127;
#pragma unroll
            for (int j = 0; j < 8; j++) Wp1[i * 8 + j] = f2bf(W1[(kq * 8 + j) * 128 + c]);
        } else if (i < 3072) {                // W2: 16 kq x 64 c
            int i2 = i - 2048;
            int kq = i2 >> 6, c = i2 & 63;
#pragma unroll
            for (int j = 0; j < 8; j++) Wp2[i2 * 8 + j] = f2bf(W2[(kq * 8 + j) * 64 + c]);
        }
        return;
    }
    __shared__ uint2 est[EPB];                       // 51.2 KB staged (src,dst)
    __shared__ unsigned int sortedPk[EPB];           // 25.6 KB dst-sorted records
    __shared__ unsigned short bIdD[EPB];             // 12.8 KB bucket id per slot
    __shared__ unsigned short bIdS[EPB];             // 12.8 KB (src keying)
    __shared__ unsigned char sByte[EPB];             //  6.4 KB src-sorted bytes
    __shared__ int histD[NB], histS[NB], startD[NB], startS[NB];
    __shared__ int gbD[NB], gbS[NB], cursD[NB], cursS[NB];
    __shared__ int s1[256];
    int t = threadIdx.x;
    for (int i = t; i < NB; i += 1024) { histD[i] = 0; histS[i] = 0; }
    __syncthreads();
    int base = blockIdx.x * EPB;
    // ---- P1: coalesced read + stage + histograms ----
    for (int i = t; i < EPB; i += 1024) {
        int s = src[base + i], d = dst[base + i];
        est[i] = make_uint2((unsigned int)s, (unsigned int)d);
        atomicAdd(&histD[d >> 8], 1);
        atomicAdd(&histS[s >> 8], 1);
    }
    __syncthreads();
    // ---- global bucket cursors (returning atomics, padded: no line sharing) ----
    for (int i = t; i < NB; i += 1024) {
        int hD = histD[i], hS = histS[i];
        gbD[i] = hD ? atomicAdd(&gcurD[i * GSTRIDE], hD) : 0;
        gbS[i] = hS ? atomicAdd(&gcurS[i * GSTRIDE], hS) : 0;
    }
    // ---- exclusive scans (256-thread pair scan over NB<=512) ----
    // D scan
    if (t < 256) {
        int a = (2 * t < NB) ? histD[2 * t] : 0;
        int b = (2 * t + 1 < NB) ? histD[2 * t + 1] : 0;
        s1[t] = a + b;
    }
    __syncthreads();
    for (int o = 1; o < 256; o <<= 1) {
        int v = 0;
        if (t < 256) v = s1[t] + (t >= o ? s1[t - o] : 0);
        __syncthreads();
        if (t < 256) s1[t] = v;
        __syncthreads();
    }
    if (t < 256) {
        int excl = (t > 0) ? s1[t - 1] : 0;
        if (2 * t < NB) { startD[2 * t] = excl; cursD[2 * t] = excl; }
        if (2 * t + 1 < NB) {
            int e2 = excl + histD[2 * t];
            startD[2 * t + 1] = e2; cursD[2 * t + 1] = e2;
        }
    }
    __syncthreads();
    // S scan
    if (t < 256) {
        int a = (2 * t < NB) ? histS[2 * t] : 0;
        int b = (2 * t + 1 < NB) ? histS[2 * t + 1] : 0;
        s1[t] = a + b;
    }
    __syncthreads();
    for (int o = 1; o < 256; o <<= 1) {
        int v = 0;
        if (t < 256) v = s1[t] + (t >= o ? s1[t - o] : 0);
        __syncthreads();
        if (t < 256) s1[t] = v;
        __syncthreads();
    }
    if (t < 256) {
        int excl = (t > 0) ? s1[t - 1] : 0;
        if (2 * t < NB) { startS[2 * t] = excl; cursS[2 * t] = excl; }
        if (2 * t + 1 < NB) {
            int e2 = excl + histS[2 * t];
            startS[2 * t + 1] = e2; cursS[2 * t + 1] = e2;
        }
    }
    __syncthreads();
    // ---- P2: LDS counting-sort scatter (both keyings, one pass over est) ----
    for (int i = t; i < EPB; i += 1024) {
        uint2 e2 = est[i];
        int s = (int)e2.x, d = (int)e2.y;
        int bd = d >> 8;
        int r = atomicAdd(&cursD[bd], 1);
        sortedPk[r] = ((unsigned int)s << 8) | (unsigned int)(d & 255);
        bIdD[r] = (unsigned short)bd;
        int bs = s >> 8;
        int r2 = atomicAdd(&cursS[bs], 1);
        sByte[r2] = (unsigned char)(s & 255);
        bIdS[r2] = (unsigned short)bs;
    }
    __syncthreads();
    // ---- P3: coalesced write-out (consecutive threads -> consecutive addrs) ----
    for (int i = t; i < EPB; i += 1024) {
        int b = bIdD[i];
        int pos = gbD[b] + (i - startD[b]);
        if (pos < BCAP) ebuf[(size_t)b * BCAP + pos] = sortedPk[i];
        int b2 = bIdS[i];
        int pos2 = gbS[b2] + (i - startS[b2]);
        if (pos2 < BCAP) ebufS[(size_t)b2 * BCAP + pos2] = sByte[i];
    }
}

// ---- R11 merged launch (kills the serialized k_bhist_scan kernel):
//   blocks [0,NB)        = per-bucket counting sort; each computes its OWN bbase
//                          via prefix tree-reduce over gcurD (R3-validated);
//                          block NB-1 writes row_ptr[N]=E.
//   blocks [NB,2NB)      = out-degree histogram -> out_norm (ex-bhist).
//   blocks [2NB,2NB+12500) = xb = bf16(x) PURE CAST — the out_norm scale moved
//                          into agg1's gather FMA (R9 proved wave-uniform
//                          broadcast loads there are fully latency-hidden),
//                          which removes xb's dependency on the histogram and
//                          lets all three phases co-schedule in ONE launch. ----
__global__ __launch_bounds__(256) void k_bsort_bhist_xb(const unsigned int* __restrict__ ebuf,
                                                        const int* __restrict__ gcurD,
                                                        int* __restrict__ csr_src,
                                                        int* __restrict__ row_ptr, float* __restrict__ in_norm,
                                                        const unsigned char* __restrict__ ebufS,
                                                        const int* __restrict__ gcurS,
                                                        float* __restrict__ out_norm,
                                                        const float* __restrict__ x,
                                                        unsigned short* __restrict__ xb) {
    __shared__ int perm[BCAP];          // 20 KB sorted srcs
    __shared__ int hist[256], cursor[256], sa[256], sb[256];
    int t = threadIdx.x;
    if (blockIdx.x >= 2 * NB) {         // ---- xb blocks: pure bf16 cast ----
        int tid = (blockIdx.x - 2 * NB) * 256 + t;   // 12500 x 256 = N*32 exact
        float4 v = ((const float4*)x)[tid];
        unsigned int lo = (unsigned int)f2bf(v.x) | ((unsigned int)f2bf(v.y) << 16);
        unsigned int hi = (unsigned int)f2bf(v.z) | ((unsigned int)f2bf(v.w) << 16);
        ((uint2*)xb)[tid] = make_uint2(lo, hi);
        return;
    }
    if (blockIdx.x >= NB) {             // ---- bhist blocks: out_norm ----
        int b = blockIdx.x - NB;
        hist[t] = 0;
        __syncthreads();
        int ne = min(gcurS[b * GSTRIDE], BCAP);
        const unsigned char* eb = ebufS + (size_t)b * BCAP;
        int nv = ne >> 2;
        const uchar4* ev = (const uchar4*)eb;
        for (int i = t; i < nv; i += 256) {
            uchar4 u = ev[i];
            atomicAdd(&hist[u.x], 1); atomicAdd(&hist[u.y], 1);
            atomicAdd(&hist[u.z], 1); atomicAdd(&hist[u.w], 1);
        }
        for (int i = (nv << 2) + t; i < ne; i += 256) atomicAdd(&hist[eb[i]], 1);
        __syncthreads();
        int node = b * 256 + t;
        if (node < N_NODES) out_norm[node] = hist[t] > 0 ? rsqrtf((float)hist[t]) : 1.0f;
        return;
    }
    // ---- sort blocks ----
    int b = blockIdx.x;
    int ne = min(gcurD[b * GSTRIDE], BCAP);
    const unsigned int* eb = ebuf + (size_t)b * BCAP;
    // own bbase: sum_{i<b} min(gcurD[i],BCAP) via 256-thread tree reduce
    int partial = 0;
    for (int i = t; i < b; i += 256) partial += min(gcurD[i * GSTRIDE], BCAP);
    sa[t] = partial;
    __syncthreads();
    for (int o = 128; o > 0; o >>= 1) {
        if (t < o) sa[t] += sa[t + o];
        __syncthreads();
    }
    int gb = sa[0];
    __syncthreads();                    // sa reused below
    hist[t] = 0;
    __syncthreads();
    for (int i = t; i < ne; i += 256) atomicAdd(&hist[eb[i] & 255u], 1);
    __syncthreads();
    sa[t] = hist[t];
    __syncthreads();
    int* cur = sa; int* nxt = sb;
    for (int o = 1; o < 256; o <<= 1) {
        int v = cur[t] + (t >= o ? cur[t - o] : 0);
        nxt[t] = v;
        __syncthreads();
        int* tmp = cur; cur = nxt; nxt = tmp;
    }
    int ex = cur[t] - hist[t];   // exclusive
    cursor[t] = ex;
    int node = b * 256 + t;
    if (node < N_NODES) {
        row_ptr[node] = gb + ex;
        in_norm[node] = hist[t] > 0 ? rsqrtf((float)hist[t]) : 1.0f;
    }
    if (b == NB - 1 && t == 0) row_ptr[N_NODES] = gb + ne;   // total edge count
    __syncthreads();
    for (int i = t; i < ne; i += 256) {
        unsigned int pk = eb[i];           // L2-warm re-read
        int pos = atomicAdd(&cursor[pk & 255u], 1);
        perm[pos] = (int)(pk >> 8);
    }
    __syncthreads();
    for (int i = t; i < ne; i += 256) csr_src[gb + i] = perm[i];
}

// ---- layer-1 aggregation: wave per dst node, 128 bf16 cols (2/lane), f32 accum ----
// CLOSED structure (R9: 3.65 TB/s L3 random-line ceiling; csr broadcast loads
// fully hidden). R11: out_norm[s] applied HERE via FMA (w8 uniform scalar loads
// — same hidden-broadcast class as csr per R9) instead of pre-scaling xb; this
// freed the xb cast from the bhist dependency. add->fma = same VALU count.
__global__ __launch_bounds__(256) void k_agg1(const unsigned short* __restrict__ xb,
                                              const int* __restrict__ row_ptr, const int* __restrict__ csr,
                                              const float* __restrict__ in_norm, const float* __restrict__ out_norm,
                                              unsigned short* __restrict__ aggb) {
    int wave = threadIdx.x >> 6, lane = threadIdx.x & 63;
    int d = blockIdx.x * 4 + wave;
    if (d >= N_NODES) return;
    int e0 = __builtin_amdgcn_readfirstlane(row_ptr[d]);
    int e1 = __builtin_amdgcn_readfirstlane(row_ptr[d + 1]);
    int col = lane << 1;
    float accL[8], accH[8];
#pragma unroll
    for (int j = 0; j < 8; j++) { accL[j] = 0.f; accH[j] = 0.f; }
    int e = e0;
    for (; e + 8 <= e1; e += 8) {
        int sI[8];
#pragma unroll
        for (int j = 0; j < 8; j++) sI[j] = __builtin_amdgcn_readfirstlane(csr[e + j]);
        float w8[8];
#pragma unroll
        for (int j = 0; j < 8; j++) w8[j] = out_norm[sI[j]];
        unsigned int v[8];
#pragma unroll
        for (int j = 0; j < 8; j++) v[j] = *(const unsigned int*)(xb + (size_t)sI[j] * 128 + col);
#pragma unroll
        for (int j = 0; j < 8; j++) {
            accL[j] = fmaf(w8[j], bf2f((unsigned short)(v[j] & 0xffffu)), accL[j]);
            accH[j] = fmaf(w8[j], bf2f((unsigned short)(v[j] >> 16)), accH[j]);
        }
    }
    if (e + 4 <= e1) {
        int sI[4];
#pragma unroll
        for (int j = 0; j < 4; j++) sI[j] = __builtin_amdgcn_readfirstlane(csr[e + j]);
        float w4[4];
#pragma unroll
        for (int j = 0; j < 4; j++) w4[j] = out_norm[sI[j]];
        unsigned int v[4];
#pragma unroll
        for (int j = 0; j < 4; j++) v[j] = *(const unsigned int*)(xb + (size_t)sI[j] * 128 + col);
#pragma unroll
        for (int j = 0; j < 4; j++) {
            accL[j] = fmaf(w4[j], bf2f((unsigned short)(v[j] & 0xffffu)), accL[j]);
            accH[j] = fmaf(w4[j], bf2f((unsigned short)(v[j] >> 16)), accH[j]);
        }
        e += 4;
    }
    if (e + 2 <= e1) {
        int sI[2];
#pragma unroll
        for (int j = 0; j < 2; j++) sI[j] = __builtin_amdgcn_readfirstlane(csr[e + j]);
        float w2[2];
#pragma unroll
        for (int j = 0; j < 2; j++) w2[j] = out_norm[sI[j]];
        unsigned int v[2];
#pragma unroll
        for (int j = 0; j < 2; j++) v[j] = *(const unsigned int*)(xb + (size_t)sI[j] * 128 + col);
#pragma unroll
        for (int j = 0; j < 2; j++) {
            accL[j] = fmaf(w2[j], bf2f((unsigned short)(v[j] & 0xffffu)), accL[j]);
            accH[j] = fmaf(w2[j], bf2f((unsigned short)(v[j] >> 16)), accH[j]);
        }
        e += 2;
    }
    if (e < e1) {
        int s = __builtin_amdgcn_readfirstlane(csr[e]);
        float w1 = out_norm[s];
        unsigned int v = *(const unsigned int*)(xb + (size_t)s * 128 + col);
        accL[0] = fmaf(w1, bf2f((unsigned short)(v & 0xffffu)), accL[0]);
        accH[0] = fmaf(w1, bf2f((unsigned short)(v >> 16)), accH[0]);
    }
    float a0 = 0.f, a1 = 0.f;
#pragma unroll
    for (int j = 0; j < 8; j++) { a0 += accL[j]; a1 += accH[j]; }
    float w = in_norm[d];
    unsigned int pk = (unsigned int)f2bf(a0 * w) | ((unsigned int)f2bf(a1 * w) << 16);
    *(unsigned int*)(aggb + (size_t)d * 128 + col) = pk;
}

// ---- fused GEMM1+GEMM2 (R10): W1/W2 B-fragments direct from L2 (48 KB
// L2-resident); LDS = zt only (16.5 KB). Near its floor (R10: -0.5us). ----
__global__ __launch_bounds__(256) void k_gemm12(const unsigned short* __restrict__ Ab,
                                                const unsigned short* __restrict__ Wp1,
                                                const unsigned short* __restrict__ Wp2,
                                                const float* __restrict__ bias1,
                                                const float* __restrict__ out_norm,
                                                float* __restrict__ z_out,
                                                unsigned short* __restrict__ tb) {
    __shared__ __align__(16) unsigned short zt[64 * 132];         // 16.5 KB zs tile
    int wave = threadIdx.x >> 6, lane = threadIdx.x & 63;
    int base = (blockIdx.x * 4 + wave) * 16;
    if (base >= N_NODES) return;
    int m = lane & 15, q = lane >> 4;
    short8 a[4];
#pragma unroll
    for (int t = 0; t < 4; t++) a[t] = *(const short8*)(Ab + (size_t)(base + m) * 128 + t * 32 + q * 8);
    f32x4 acc[8];
#pragma unroll
    for (int c = 0; c < 8; c++) acc[c] = (f32x4)(0.f);
#pragma unroll
    for (int ct = 0; ct < 8; ct++) {
#pragma unroll
        for (int t = 0; t < 4; t++) {
            short8 b = *(const short8*)(Wp1 + ((size_t)((t * 4 + q) * 128 + ct * 16 + m)) * 8);
            acc[ct] = __builtin_amdgcn_mfma_f32_16x16x32_bf16(a[t], b, acc[ct], 0, 0, 0);
        }
    }
    float onr[4];
#pragma unroll
    for (int i = 0; i < 4; i++) onr[i] = out_norm[base + q * 4 + i];
#pragma unroll
    for (int ct = 0; ct < 8; ct++) {
        int col = ct * 16 + m;
        float bv = bias1[col];
#pragma unroll
        for (int i = 0; i < 4; i++) {
            int row = base + q * 4 + i;
            float v = acc[ct][i] + bv;
            v = v > 0.f ? v : 0.f;
            z_out[(size_t)row * 128 + col] = v;
            zt[(wave * 16 + q * 4 + i) * 132 + col] = f2bf(v * onr[i]);
        }
    }
    // zt rows wave-private; intra-wave lgkmcnt suffices, no barrier.
    short8 a2[4];
#pragma unroll
    for (int t = 0; t < 4; t++) a2[t] = *(const short8*)(zt + (wave * 16 + m) * 132 + t * 32 + q * 8);
    f32x4 acc2[4];
#pragma unroll
    for (int c = 0; c < 4; c++) acc2[c] = (f32x4)(0.f);
#pragma unroll
    for (int ct = 0; ct < 4; ct++) {
#pragma unroll
        for (int t = 0; t < 4; t++) {
            short8 b = *(const short8*)(Wp2 + ((size_t)((t * 4 + q) * 64 + ct * 16 + m)) * 8);
            acc2[ct] = __builtin_amdgcn_mfma_f32_16x16x32_bf16(a2[t], b, acc2[ct], 0, 0, 0);
        }
    }
#pragma unroll
    for (int ct = 0; ct < 4; ct++) {
        int col = ct * 16 + m;
#pragma unroll
        for (int i = 0; i < 4; i++) {
            int row = base + q * 4 + i;
            tb[(size_t)row * 64 + col] = f2bf(acc2[ct][i]);
        }
    }
}

// ---- layer-2 aggregation: TWO edges per wave-instruction (R8). CLOSED
// (R8 pairing null-ish, R9 readlane null -> L3 random-line BW-bound). ----
__global__ __launch_bounds__(256) void k_agg2(const unsigned short* __restrict__ tb,
                                              const int* __restrict__ row_ptr, const int* __restrict__ csr,
                                              const float* __restrict__ in_norm, const float* __restrict__ b2,
                                              float* __restrict__ out_h2) {
    int wave = threadIdx.x >> 6, lane = threadIdx.x & 63;
    int half = lane >> 5, li = lane & 31;
    int d = blockIdx.x * 4 + wave;
    if (d >= N_NODES) return;
    int e0 = __builtin_amdgcn_readfirstlane(row_ptr[d]);
    int e1 = __builtin_amdgcn_readfirstlane(row_ptr[d + 1]);
    int col = li << 1;                 // this lane's 2 cols within its half's edge
    float accA[8], accB[8];
#pragma unroll
    for (int j = 0; j < 8; j++) { accA[j] = 0.f; accB[j] = 0.f; }
    int e = e0;
    for (; e + 16 <= e1; e += 16) {    // 8 pair-loads = 16 edges
        int sI[8];
#pragma unroll
        for (int j = 0; j < 8; j++) {
            int sA = __builtin_amdgcn_readfirstlane(csr[e + 2 * j]);
            int sB = __builtin_amdgcn_readfirstlane(csr[e + 2 * j + 1]);
            sI[j] = half ? sB : sA;
        }
        unsigned int v[8];
#pragma unroll
        for (int j = 0; j < 8; j++) v[j] = *(const unsigned int*)(tb + (size_t)sI[j] * 64 + col);
#pragma unroll
        for (int j = 0; j < 8; j++) {
            accA[j] += bf2f((unsigned short)(v[j] & 0xffffu));
            accB[j] += bf2f((unsigned short)(v[j] >> 16));
        }
    }
    if (e + 8 <= e1) {                 // 4 pairs
        int sI[4];
#pragma unroll
        for (int j = 0; j < 4; j++) {
            int sA = __builtin_amdgcn_readfirstlane(csr[e + 2 * j]);
            int sB = __builtin_amdgcn_readfirstlane(csr[e + 2 * j + 1]);
            sI[j] = half ? sB : sA;
        }
        unsigned int v[4];
#pragma unroll
        for (int j = 0; j < 4; j++) v[j] = *(const unsigned int*)(tb + (size_t)sI[j] * 64 + col);
#pragma unroll
        for (int j = 0; j < 4; j++) {
            accA[j] += bf2f((unsigned short)(v[j] & 0xffffu));
            accB[j] += bf2f((unsigned short)(v[j] >> 16));
        }
        e += 8;
    }
    if (e + 4 <= e1) {                 // 2 pairs
        int sI[2];
#pragma unroll
        for (int j = 0; j < 2; j++) {
            int sA = __builtin_amdgcn_readfirstlane(csr[e + 2 * j]);
            int sB = __builtin_amdgcn_readfirstlane(csr[e + 2 * j + 1]);
            sI[j] = half ? sB : sA;
        }
        unsigned int v[2];
#pragma unroll
        for (int j = 0; j < 2; j++) v[j] = *(const unsigned int*)(tb + (size_t)sI[j] * 64 + col);
#pragma unroll
        for (int j = 0; j < 2; j++) {
            accA[j] += bf2f((unsigned short)(v[j] & 0xffffu));
            accB[j] += bf2f((unsigned short)(v[j] >> 16));
        }
        e += 2 * 2;
    }
    if (e + 2 <= e1) {                 // 1 pair
        int sA = __builtin_amdgcn_readfirstlane(csr[e]);
        int sB = __builtin_amdgcn_readfirstlane(csr[e + 1]);
        int s = half ? sB : sA;
        unsigned int v = *(const unsigned int*)(tb + (size_t)s * 64 + col);
        accA[0] += bf2f((unsigned short)(v & 0xffffu));
        accB[0] += bf2f((unsigned short)(v >> 16));
        e += 2;
    }
    if (e < e1) {                      // odd edge: half 0 only (avoid double count)
        int s = __builtin_amdgcn_readfirstlane(csr[e]);
        unsigned int v = *(const unsigned int*)(tb + (size_t)s * 64 + col);
        if (half == 0) {
            accA[0] += bf2f((unsigned short)(v & 0xffffu));
            accB[0] += bf2f((unsigned short)(v >> 16));
        }
    }
    float a0 = 0.f, a1 = 0.f;
#pragma unroll
    for (int j = 0; j < 8; j++) { a0 += accA[j]; a1 += accB[j]; }
    a0 += __shfl_xor(a0, 32);          // combine the two halves' edge subsets
    a1 += __shfl_xor(a1, 32);
    if (half == 0) {
        float w = in_norm[d];
        float2 r;
        r.x = a0 * w + b2[col];
        r.y = a1 * w + b2[col + 1];
        *(float2*)(out_h2 + (size_t)d * 64 + col) = r;
    }
}

extern "C" void kernel_launch(void* const* d_in, const int* in_sizes, int n_in,
                              void* d_out, int out_size, void* d_ws, size_t ws_size,
                              hipStream_t stream) {
    const float* x   = (const float*)d_in[0];
    const int*   src = (const int*)d_in[1];
    const int*   dst = (const int*)d_in[2];
    const float* W1  = (const float*)d_in[3];
    const float* b1  = (const float*)d_in[4];
    const float* W2  = (const float*)d_in[5];
    const float* b2  = (const float*)d_in[6];
    float* out_h2 = (float*)d_out;                     // [N,64]
    float* out_z  = (float*)d_out + N_NODES * 64;      // [N,128]

    char* ws = (char*)d_ws;
    size_t off = 0;
    auto alloc = [&](size_t bytes) -> char* {
        char* p = ws + off;
        off = (off + bytes + 255) & ~(size_t)255;
        return p;
    };
    int* gcurD    = (int*)alloc(NB * GSTRIDE * 4);     // padded: 1 counter / 64B line
    int* gcurS    = (int*)alloc(NB * GSTRIDE * 4);     // contiguous with gcurD: one memset
    int* row_ptr  = (int*)alloc((N_NODES + 1) * 4);
    float* out_norm = (float*)alloc(N_NODES * 4);
    float* in_norm  = (float*)alloc(N_NODES * 4);
    unsigned int* ebuf = (unsigned int*)alloc((size_t)NB * BCAP * 4);        // 8.0 MB
    unsigned char* ebufS = (unsigned char*)alloc((size_t)NB * BCAP);         // 2.0 MB
    int* csr_src  = (int*)alloc((size_t)N_EDGES * 4);
    unsigned short* Wp1 = (unsigned short*)alloc(2048 * 8 * 2);
    unsigned short* Wp2 = (unsigned short*)alloc(1024 * 8 * 2);
    unsigned short* xb    = (unsigned short*)alloc((size_t)N_NODES * 128 * 2);
    unsigned short* agg1b = (unsigned short*)alloc((size_t)N_NODES * 128 * 2);
    unsigned short* tb    = (unsigned short*)alloc((size_t)N_NODES * 64 * 2);  // bf16 t
    (void)ws_size; (void)in_sizes; (void)n_in; (void)out_size;

    const size_t gcur_pad = ((size_t)(NB * GSTRIDE * 4) + 255) & ~(size_t)255;
    hipMemsetAsync(gcurD, 0, gcur_pad + (size_t)NB * GSTRIDE * 4, stream);   // covers gcurD+gcurS

    const int GD_AGG = (N_NODES + 3) / 4;       // 25000
    const int GD_GEMM = (N_NODES / 16 + 3) / 4; // 1563
    const int GD_XB = N_NODES * 32 / 256;       // 12500

    k_part<<<PART_BLOCKS + 3, 1024, 0, stream>>>(src, dst, gcurD, gcurS, ebuf, ebufS, W1, W2, Wp1, Wp2);
    k_bsort_bhist_xb<<<2 * NB + GD_XB, 256, 0, stream>>>(ebuf, gcurD, csr_src, row_ptr, in_norm,
                                                         ebufS, gcurS, out_norm, x, xb);
    k_agg1<<<GD_AGG, 256, 0, stream>>>(xb, row_ptr, csr_src, in_norm, out_norm, agg1b);
    k_gemm12<<<GD_GEMM, 256, 0, stream>>>(agg1b, Wp1, Wp2, b1, out_norm, out_z, tb);
    k_agg2<<<GD_AGG, 256, 0, stream>>>(tb, row_ptr, csr_src, in_norm, b2, out_h2);
}